// Round 9
// baseline (250.792 us; speedup 1.0000x reference)
//
#include <hip/hip_runtime.h>
#include <hip/hip_bf16.h>

typedef __bf16 bf16x8_t __attribute__((ext_vector_type(8)));
typedef float f32x4_t __attribute__((ext_vector_type(4)));

#define SCALE_ZB 7.2134752044448169f   // 5 * log2(e): logits in log2 domain
#define LN2 0.69314718055994531f
#define E2(x) __builtin_amdgcn_exp2f(x)
#define LG2(x) __builtin_amdgcn_logf(x)

// ws byte offsets
#define WS_ACC   0u        // 5 floats used
#define WS_CNT   256u      // int[2048]
#define WS_BASE  8448u     // int[2048]
#define WS_CUR   16640u    // int[2048]
#define WS_PERM  24832u    // int[65536]
#define WS_ANC   294912u   // bf16[262144] in B-fragment order (512 KB)
#define WS_PART  819200u   // float2[65536*4]: per-row (m,s) per M-quarter (2 MB)
#define WS_ZERO  8448u     // zero acc + cnt only
// acc: 0 posdot_raw, 1 zsq, 2 hsq, 3 l2se_sum, 4 cent_ssq_over_n

// ---- anchors f32 -> bf16 packed in MFMA B-fragment order + label histogram ----
// layout: [chunk c 0..127][kk 0..3][lane 0..63][e 0..7]
// lane=(g<<4)|l15 holds anchor (c*16+l15), k = kk*32 + g*8 + e
__global__ void prepHist(const float* __restrict__ anc, __bf16* __restrict__ out,
                         const int* __restrict__ labels, int* __restrict__ cnt) {
    int i = blockIdx.x * 256 + threadIdx.x;   // 0..65535
    atomicAdd(&cnt[labels[i]], 1);
    if (i < 32768) {
        int m = i >> 4, k0 = (i & 15) << 3;
        int kk = k0 >> 5, g = (k0 >> 3) & 3, l15 = m & 15, c = m >> 4;
        int lane = (g << 4) | l15;
        int base = (((c << 2) + kk) << 9) + (lane << 3);
        const float4* a4 = (const float4*)anc + (size_t)m * 32 + (k0 >> 2);
        float4 f0 = a4[0], f1 = a4[1];
        bf16x8_t pk;
        pk[0] = (__bf16)f0.x; pk[1] = (__bf16)f0.y; pk[2] = (__bf16)f0.z; pk[3] = (__bf16)f0.w;
        pk[4] = (__bf16)f1.x; pk[5] = (__bf16)f1.y; pk[6] = (__bf16)f1.z; pk[7] = (__bf16)f1.w;
        *(bf16x8_t*)&out[base] = pk;
    }
}

__global__ void scanK(const int* __restrict__ cnt, int* __restrict__ base,
                      int* __restrict__ cursor) {
    __shared__ int wsum[4];
    int t = threadIdx.x, lane = t & 63, w = t >> 6;
    int c[8], tot = 0;
    #pragma unroll
    for (int q = 0; q < 8; ++q) { c[q] = cnt[t * 8 + q]; tot += c[q]; }
    int sc = tot;
    #pragma unroll
    for (int off = 1; off < 64; off <<= 1) {
        int o = __shfl_up(sc, off);
        if (lane >= off) sc += o;
    }
    if (lane == 63) wsum[w] = sc;
    __syncthreads();
    int woff = 0;
    for (int ww = 0; ww < w; ++ww) woff += wsum[ww];
    int ex = woff + sc - tot;
    #pragma unroll
    for (int q = 0; q < 8; ++q) {
        base[t * 8 + q] = ex;
        cursor[t * 8 + q] = ex;
        ex += c[q];
    }
}

__global__ void scatK(const int* __restrict__ labels, int* __restrict__ cursor,
                      int* __restrict__ perm) {
    int i = blockIdx.x * 256 + threadIdx.x;
    int l = labels[i];
    int p = atomicAdd(&cursor[l], 1);
    perm[p] = i;
}

// Homogeneous: 2048 blocks x 4 waves. Block b: rows [b*32, b*32+32).
// Wave w: M-quarter w (512 anchors, 32 chunks). No LDS, no barriers.
// Wave 2 additionally gathers centroid for label b in its tail.
__launch_bounds__(256)
__global__ void uniK(const float* __restrict__ z,
                     const float* __restrict__ he,
                     const float* __restrict__ hc,
                     const float* __restrict__ ancf,
                     const int* __restrict__ labels,
                     const __bf16* __restrict__ ancb,
                     const int* __restrict__ cnt,
                     const int* __restrict__ basep,
                     const int* __restrict__ perm,
                     float* __restrict__ acc,
                     float2* __restrict__ part) {
    const int tid  = threadIdx.x;
    const int lane = tid & 63;
    const int q    = tid >> 6;          // wave = M-quarter
    const int bid  = blockIdx.x;
    const int l15  = lane & 15, g = lane >> 4;
    const int R0   = bid << 5;          // 32 rows per block

    // ---- h-align slice: 8 float4 pairs per thread, coalesced grid-stride ----
    float hp = 0.f;
    {
        int gt = (bid << 8) + tid;       // 0..524287
        const float4* hev = (const float4*)he;
        const float4* hcv = (const float4*)hc;
        #pragma unroll 4
        for (int i = 0; i < 8; ++i) {
            float4 e = hev[(size_t)i * 524288 + gt];
            float4 c = hcv[(size_t)i * 524288 + gt];
            float dx = e.x - c.x, dy = e.y - c.y, dz = e.z - c.z, dw = e.w - c.w;
            hp += dx * dx + dy * dy + dz * dz + dw * dw;
        }
    }

    // ---- A-fragments from z (same 32 rows for all 4 waves -> L1 shared) ----
    bf16x8_t Af[2][4];
    float sp = 0.f;
    #pragma unroll
    for (int rf = 0; rf < 2; ++rf) {
        int row = R0 + (rf << 4) + l15;
        const float4* zr = (const float4*)z + ((size_t)row << 5);
        const float4* ar;
        if (q == 0) {
            int lb = labels[row];
            ar = (const float4*)ancf + ((size_t)lb << 5);
        }
        #pragma unroll
        for (int kk = 0; kk < 4; ++kk) {
            int qq = (kk << 3) + (g << 1);
            float4 z0 = zr[qq], z1 = zr[qq + 1];
            if (q == 0) {
                float4 a0 = ar[qq], a1 = ar[qq + 1];
                sp += z0.x*a0.x + z0.y*a0.y + z0.z*a0.z + z0.w*a0.w
                    + z1.x*a1.x + z1.y*a1.y + z1.z*a1.z + z1.w*a1.w;
            } else if (q == 1) {
                sp += z0.x*z0.x + z0.y*z0.y + z0.z*z0.z + z0.w*z0.w
                    + z1.x*z1.x + z1.y*z1.y + z1.z*z1.z + z1.w*z1.w;
            }
            bf16x8_t pk;
            pk[0] = (__bf16)(z0.x * SCALE_ZB); pk[1] = (__bf16)(z0.y * SCALE_ZB);
            pk[2] = (__bf16)(z0.z * SCALE_ZB); pk[3] = (__bf16)(z0.w * SCALE_ZB);
            pk[4] = (__bf16)(z1.x * SCALE_ZB); pk[5] = (__bf16)(z1.y * SCALE_ZB);
            pk[6] = (__bf16)(z1.z * SCALE_ZB); pk[7] = (__bf16)(z1.w * SCALE_ZB);
            Af[rf][kk] = pk;
        }
    }
    #pragma unroll
    for (int off = 32; off; off >>= 1) {
        sp += __shfl_xor(sp, off);
        hp += __shfl_xor(hp, off);
    }
    if (lane == 0) {
        atomicAdd(&acc[2], hp);
        if (q < 2) atomicAdd(q == 0 ? &acc[0] : &acc[1], sp);
    }

    // ---- main loop: 32 chunks (quarter q), 4-deep rotation, batched-2 LSE ----
    float m0[4], s0[4], m1[4], s1[4];
    #pragma unroll
    for (int r = 0; r < 4; ++r) { m0[r] = -1.0e30f; s0[r] = 0.f; m1[r] = -1.0e30f; s1[r] = 0.f; }

    const bf16x8_t* Bp = (const bf16x8_t*)ancb + (q << 13);   // quarter base

#define LOADB(Bx, cc) { _Pragma("unroll") \
    for (int kk = 0; kk < 4; ++kk) Bx[kk] = Bp[((((cc) << 2) | kk) << 6) + lane]; }

#define CHUNK2(Bx, By) { \
    f32x4_t aA0 = {0.f,0.f,0.f,0.f}, aB0 = {0.f,0.f,0.f,0.f}; \
    f32x4_t aA1 = {0.f,0.f,0.f,0.f}, aB1 = {0.f,0.f,0.f,0.f}; \
    _Pragma("unroll") \
    for (int kk = 0; kk < 4; ++kk) { \
        aA0 = __builtin_amdgcn_mfma_f32_16x16x32_bf16(Af[0][kk], Bx[kk], aA0, 0, 0, 0); \
        aB0 = __builtin_amdgcn_mfma_f32_16x16x32_bf16(Af[1][kk], Bx[kk], aB0, 0, 0, 0); \
    } \
    _Pragma("unroll") \
    for (int kk = 0; kk < 4; ++kk) { \
        aA1 = __builtin_amdgcn_mfma_f32_16x16x32_bf16(Af[0][kk], By[kk], aA1, 0, 0, 0); \
        aB1 = __builtin_amdgcn_mfma_f32_16x16x32_bf16(Af[1][kk], By[kk], aB1, 0, 0, 0); \
    } \
    _Pragma("unroll") \
    for (int r = 0; r < 4; ++r) { \
        { \
            float v0 = aA0[r], v1 = aA1[r]; \
            float nm = fmaxf(fmaxf(v0, v1), m0[r]); \
            s0[r] = s0[r] * E2(m0[r] - nm) + E2(v0 - nm) + E2(v1 - nm); \
            m0[r] = nm; \
        } \
        { \
            float v0 = aB0[r], v1 = aB1[r]; \
            float nm = fmaxf(fmaxf(v0, v1), m1[r]); \
            s1[r] = s1[r] * E2(m1[r] - nm) + E2(v0 - nm) + E2(v1 - nm); \
            m1[r] = nm; \
        } \
    } }

    bf16x8_t Ba[4], Bb[4], Bc[4], Bd[4];
    LOADB(Ba, 0) LOADB(Bb, 1) LOADB(Bc, 2) LOADB(Bd, 3)

    for (int c = 0; c < 32; c += 4) {
        CHUNK2(Ba, Bb)
        if (c < 28) { LOADB(Ba, c + 4) LOADB(Bb, c + 5) }
        CHUNK2(Bc, Bd)
        if (c < 28) { LOADB(Bc, c + 6) LOADB(Bd, c + 7) }
    }
#undef LOADB
#undef CHUNK2

    // ---- merge (m,s) across the 16 anchor-lanes; write quarter partials ----
    #pragma unroll
    for (int r = 0; r < 4; ++r) {
        #pragma unroll
        for (int off = 1; off < 16; off <<= 1) {
            float om = __shfl_xor(m0[r], off), os = __shfl_xor(s0[r], off);
            float nm = fmaxf(m0[r], om);
            s0[r] = s0[r] * E2(m0[r] - nm) + os * E2(om - nm);
            m0[r] = nm;
            om = __shfl_xor(m1[r], off); os = __shfl_xor(s1[r], off);
            nm = fmaxf(m1[r], om);
            s1[r] = s1[r] * E2(m1[r] - nm) + os * E2(om - nm);
            m1[r] = nm;
        }
    }
    if (l15 == 0) {
        #pragma unroll
        for (int r = 0; r < 4; ++r) {
            int row0 = R0 + (g << 2) + r;
            part[(row0 << 2) + q]        = make_float2(m0[r], s0[r]);
            part[((row0 + 16) << 2) + q] = make_float2(m1[r], s1[r]);
        }
    }

    // ---- centroid tail: wave 2 handles label bid ----
    if (q == 2) {
        const int n = cnt[bid], bs = basep[bid];
        float ax = 0.f, ay = 0.f;
        const float2* z2 = (const float2*)z;
        for (int e0 = 0; e0 < n; e0 += 64) {
            int pe = (e0 + lane < n) ? perm[bs + e0 + lane] : 0;
            int c2 = n - e0; if (c2 > 64) c2 = 64;
            int j = 0;
            for (; j + 3 < c2; j += 4) {
                int r0 = __shfl(pe, j), r1 = __shfl(pe, j + 1);
                int r2 = __shfl(pe, j + 2), r3 = __shfl(pe, j + 3);
                float2 v0 = z2[((size_t)r0 << 6) + lane];
                float2 v1 = z2[((size_t)r1 << 6) + lane];
                float2 v2 = z2[((size_t)r2 << 6) + lane];
                float2 v3 = z2[((size_t)r3 << 6) + lane];
                ax += v0.x + v1.x + v2.x + v3.x;
                ay += v0.y + v1.y + v2.y + v3.y;
            }
            for (; j < c2; ++j) {
                int r0 = __shfl(pe, j);
                float2 v0 = z2[((size_t)r0 << 6) + lane];
                ax += v0.x; ay += v0.y;
            }
        }
        float ssq = ax * ax + ay * ay;
        #pragma unroll
        for (int off = 32; off; off >>= 1) ssq += __shfl_xor(ssq, off);
        if (lane == 0) atomicAdd(&acc[4], ssq / fmaxf((float)n, 1.f));
    }
}

// ---- merge the four M-quarter partials per row, LSE, sum ----
__global__ void mergeL(const float4* __restrict__ part4, float* __restrict__ acc) {
    int t = blockIdx.x * 256 + threadIdx.x;   // 0..65535 rows
    float4 A = part4[t << 1], Bq = part4[(t << 1) + 1];   // (m0,s0,m1,s1),(m2,s2,m3,s3)
    float nm = fmaxf(fmaxf(A.x, A.z), fmaxf(Bq.x, Bq.z));
    float s = A.y * E2(A.x - nm) + A.w * E2(A.z - nm)
            + Bq.y * E2(Bq.x - nm) + Bq.w * E2(Bq.z - nm);
    float lse = nm + LG2(s);
    #pragma unroll
    for (int off = 32; off; off >>= 1) lse += __shfl_xor(lse, off);
    if ((threadIdx.x & 63) == 0) atomicAdd(&acc[3], lse);
}

__global__ void finalize(const float* __restrict__ acc, float* __restrict__ out) {
    float lc   = (LN2 * acc[3] - 5.0f * acc[0]) * (1.0f / 65536.0f);
    float cent = (acc[1] - acc[4]) * (1.0f / 8388608.0f);
    float hal  = acc[2] * (1.0f / 16777216.0f);
    out[0] = lc + 0.05f * cent + 0.1f * hal;
}

extern "C" void kernel_launch(void* const* d_in, const int* in_sizes, int n_in,
                              void* d_out, int out_size, void* d_ws, size_t ws_size,
                              hipStream_t stream) {
    const float* z      = (const float*)d_in[0];
    const float* he     = (const float*)d_in[1];
    const float* hc     = (const float*)d_in[2];
    const float* anc    = (const float*)d_in[3];
    const int*   labels = (const int*)d_in[4];

    char* ws = (char*)d_ws;
    float*  acc    = (float*)(ws + WS_ACC);
    int*    cnt    = (int*)(ws + WS_CNT);
    int*    basep  = (int*)(ws + WS_BASE);
    int*    cursor = (int*)(ws + WS_CUR);
    int*    perm   = (int*)(ws + WS_PERM);
    __bf16* ancb   = (__bf16*)(ws + WS_ANC);
    float2* part   = (float2*)(ws + WS_PART);

    hipMemsetAsync(d_ws, 0, WS_ZERO, stream);
    prepHist<<<256, 256, 0, stream>>>(anc, ancb, labels, cnt);
    scanK<<<1, 256, 0, stream>>>(cnt, basep, cursor);
    scatK<<<256, 256, 0, stream>>>(labels, cursor, perm);
    uniK<<<2048, 256, 0, stream>>>(z, he, hc, anc, labels, ancb, cnt, basep, perm, acc, part);
    mergeL<<<256, 256, 0, stream>>>((const float4*)part, acc);
    finalize<<<1, 1, 0, stream>>>(acc, (float*)d_out);
}

// Round 10
// 122.833 us; speedup vs baseline: 2.0417x; 2.0417x over previous
//
#include <hip/hip_runtime.h>
#include <hip/hip_bf16.h>

typedef __bf16 bf16x8_t __attribute__((ext_vector_type(8)));
typedef float f32x4_t __attribute__((ext_vector_type(4)));

#define SCALE_ZB 7.2134752044448169f   // 5 * log2(e): logits in log2 domain
#define LN2 0.69314718055994531f
#define E2(x) __builtin_amdgcn_exp2f(x)
#define LG2(x) __builtin_amdgcn_logf(x)

// ws byte offsets
#define WS_CNT   256u       // int[2048]
#define WS_BASE  8448u      // int[2048]
#define WS_CUR   16640u     // int[2048]
#define WS_PERM  24832u     // int[65536]
#define WS_ANC   294912u    // bf16[262144] in B-fragment order (512 KB)
#define WS_PART  819200u    // float2[65536*4]: per-row (m,s) per M-quarter (2 MB)
#define WS_WSUM  2916352u   // float4[8192]: per-wave (hp,pos,zsq,cent)
#define WS_LSE   3047424u   // float[256]: per-mergeL-block lse partial
#define WS_ZERO  8448u      // zero cnt region only

// ---- anchors f32 -> bf16 packed in MFMA B-fragment order + label histogram ----
__global__ void prepHist(const float* __restrict__ anc, __bf16* __restrict__ out,
                         const int* __restrict__ labels, int* __restrict__ cnt) {
    int i = blockIdx.x * 256 + threadIdx.x;   // 0..65535
    atomicAdd(&cnt[labels[i]], 1);
    if (i < 32768) {
        int m = i >> 4, k0 = (i & 15) << 3;
        int kk = k0 >> 5, g = (k0 >> 3) & 3, l15 = m & 15, c = m >> 4;
        int lane = (g << 4) | l15;
        int base = (((c << 2) + kk) << 9) + (lane << 3);
        const float4* a4 = (const float4*)anc + (size_t)m * 32 + (k0 >> 2);
        float4 f0 = a4[0], f1 = a4[1];
        bf16x8_t pk;
        pk[0] = (__bf16)f0.x; pk[1] = (__bf16)f0.y; pk[2] = (__bf16)f0.z; pk[3] = (__bf16)f0.w;
        pk[4] = (__bf16)f1.x; pk[5] = (__bf16)f1.y; pk[6] = (__bf16)f1.z; pk[7] = (__bf16)f1.w;
        *(bf16x8_t*)&out[base] = pk;
    }
}

__global__ void scanK(const int* __restrict__ cnt, int* __restrict__ base,
                      int* __restrict__ cursor) {
    __shared__ int wsum[4];
    int t = threadIdx.x, lane = t & 63, w = t >> 6;
    int c[8], tot = 0;
    #pragma unroll
    for (int q = 0; q < 8; ++q) { c[q] = cnt[t * 8 + q]; tot += c[q]; }
    int sc = tot;
    #pragma unroll
    for (int off = 1; off < 64; off <<= 1) {
        int o = __shfl_up(sc, off);
        if (lane >= off) sc += o;
    }
    if (lane == 63) wsum[w] = sc;
    __syncthreads();
    int woff = 0;
    for (int ww = 0; ww < w; ++ww) woff += wsum[ww];
    int ex = woff + sc - tot;
    #pragma unroll
    for (int q = 0; q < 8; ++q) {
        base[t * 8 + q] = ex;
        cursor[t * 8 + q] = ex;
        ex += c[q];
    }
}

__global__ void scatK(const int* __restrict__ labels, int* __restrict__ cursor,
                      int* __restrict__ perm) {
    int i = blockIdx.x * 256 + threadIdx.x;
    int l = labels[i];
    int p = atomicAdd(&cursor[l], 1);
    perm[p] = i;
}

// Homogeneous: 2048 blocks x 4 waves; block b owns rows [b*32,b*32+32),
// wave q = M-quarter. NO global atomics anywhere: per-wave slot stores only.
__launch_bounds__(256)
__global__ void uniK(const float* __restrict__ z,
                     const float* __restrict__ he,
                     const float* __restrict__ hc,
                     const float* __restrict__ ancf,
                     const int* __restrict__ labels,
                     const __bf16* __restrict__ ancb,
                     const int* __restrict__ cnt,
                     const int* __restrict__ basep,
                     const int* __restrict__ perm,
                     float4* __restrict__ wsum,
                     float2* __restrict__ part) {
    const int tid  = threadIdx.x;
    const int lane = tid & 63;
    const int q    = tid >> 6;          // wave = M-quarter
    const int bid  = blockIdx.x;
    const int l15  = lane & 15, g = lane >> 4;
    const int R0   = bid << 5;          // 32 rows per block
    const int gw   = (bid << 2) + q;

    // ---- h-align slice ----
    float hp = 0.f;
    {
        int gt = (bid << 8) + tid;
        const float4* hev = (const float4*)he;
        const float4* hcv = (const float4*)hc;
        #pragma unroll 4
        for (int i = 0; i < 8; ++i) {
            float4 e = hev[(size_t)i * 524288 + gt];
            float4 c = hcv[(size_t)i * 524288 + gt];
            float dx = e.x - c.x, dy = e.y - c.y, dz = e.z - c.z, dw = e.w - c.w;
            hp += dx * dx + dy * dy + dz * dz + dw * dw;
        }
    }

    // ---- A-fragments from z; q0 pos-dot, q1 zsq ----
    bf16x8_t Af[2][4];
    float sp = 0.f;
    #pragma unroll
    for (int rf = 0; rf < 2; ++rf) {
        int row = R0 + (rf << 4) + l15;
        const float4* zr = (const float4*)z + ((size_t)row << 5);
        const float4* ar;
        if (q == 0) {
            int lb = labels[row];
            ar = (const float4*)ancf + ((size_t)lb << 5);
        }
        #pragma unroll
        for (int kk = 0; kk < 4; ++kk) {
            int qq = (kk << 3) + (g << 1);
            float4 z0 = zr[qq], z1 = zr[qq + 1];
            if (q == 0) {
                float4 a0 = ar[qq], a1 = ar[qq + 1];
                sp += z0.x*a0.x + z0.y*a0.y + z0.z*a0.z + z0.w*a0.w
                    + z1.x*a1.x + z1.y*a1.y + z1.z*a1.z + z1.w*a1.w;
            } else if (q == 1) {
                sp += z0.x*z0.x + z0.y*z0.y + z0.z*z0.z + z0.w*z0.w
                    + z1.x*z1.x + z1.y*z1.y + z1.z*z1.z + z1.w*z1.w;
            }
            bf16x8_t pk;
            pk[0] = (__bf16)(z0.x * SCALE_ZB); pk[1] = (__bf16)(z0.y * SCALE_ZB);
            pk[2] = (__bf16)(z0.z * SCALE_ZB); pk[3] = (__bf16)(z0.w * SCALE_ZB);
            pk[4] = (__bf16)(z1.x * SCALE_ZB); pk[5] = (__bf16)(z1.y * SCALE_ZB);
            pk[6] = (__bf16)(z1.z * SCALE_ZB); pk[7] = (__bf16)(z1.w * SCALE_ZB);
            Af[rf][kk] = pk;
        }
    }
    #pragma unroll
    for (int off = 32; off; off >>= 1) {
        sp += __shfl_xor(sp, off);
        hp += __shfl_xor(hp, off);
    }

    // ---- main loop: 32 chunks (quarter q), 4-deep rotation, batched-2 LSE ----
    float m0[4], s0[4], m1[4], s1[4];
    #pragma unroll
    for (int r = 0; r < 4; ++r) { m0[r] = -1.0e30f; s0[r] = 0.f; m1[r] = -1.0e30f; s1[r] = 0.f; }

    const bf16x8_t* Bp = (const bf16x8_t*)ancb + (q << 13);

#define LOADB(Bx, cc) { _Pragma("unroll") \
    for (int kk = 0; kk < 4; ++kk) Bx[kk] = Bp[((((cc) << 2) | kk) << 6) + lane]; }

#define CHUNK2(Bx, By) { \
    f32x4_t aA0 = {0.f,0.f,0.f,0.f}, aB0 = {0.f,0.f,0.f,0.f}; \
    f32x4_t aA1 = {0.f,0.f,0.f,0.f}, aB1 = {0.f,0.f,0.f,0.f}; \
    _Pragma("unroll") \
    for (int kk = 0; kk < 4; ++kk) { \
        aA0 = __builtin_amdgcn_mfma_f32_16x16x32_bf16(Af[0][kk], Bx[kk], aA0, 0, 0, 0); \
        aB0 = __builtin_amdgcn_mfma_f32_16x16x32_bf16(Af[1][kk], Bx[kk], aB0, 0, 0, 0); \
    } \
    _Pragma("unroll") \
    for (int kk = 0; kk < 4; ++kk) { \
        aA1 = __builtin_amdgcn_mfma_f32_16x16x32_bf16(Af[0][kk], By[kk], aA1, 0, 0, 0); \
        aB1 = __builtin_amdgcn_mfma_f32_16x16x32_bf16(Af[1][kk], By[kk], aB1, 0, 0, 0); \
    } \
    _Pragma("unroll") \
    for (int r = 0; r < 4; ++r) { \
        { \
            float v0 = aA0[r], v1 = aA1[r]; \
            float nm = fmaxf(fmaxf(v0, v1), m0[r]); \
            s0[r] = s0[r] * E2(m0[r] - nm) + E2(v0 - nm) + E2(v1 - nm); \
            m0[r] = nm; \
        } \
        { \
            float v0 = aB0[r], v1 = aB1[r]; \
            float nm = fmaxf(fmaxf(v0, v1), m1[r]); \
            s1[r] = s1[r] * E2(m1[r] - nm) + E2(v0 - nm) + E2(v1 - nm); \
            m1[r] = nm; \
        } \
    } }

    bf16x8_t Ba[4], Bb[4], Bc[4], Bd[4];
    LOADB(Ba, 0) LOADB(Bb, 1) LOADB(Bc, 2) LOADB(Bd, 3)

    for (int c = 0; c < 32; c += 4) {
        CHUNK2(Ba, Bb)
        if (c < 28) { LOADB(Ba, c + 4) LOADB(Bb, c + 5) }
        CHUNK2(Bc, Bd)
        if (c < 28) { LOADB(Bc, c + 6) LOADB(Bd, c + 7) }
    }
#undef LOADB
#undef CHUNK2

    // ---- merge (m,s) across the 16 anchor-lanes; write quarter partials ----
    #pragma unroll
    for (int r = 0; r < 4; ++r) {
        #pragma unroll
        for (int off = 1; off < 16; off <<= 1) {
            float om = __shfl_xor(m0[r], off), os = __shfl_xor(s0[r], off);
            float nm = fmaxf(m0[r], om);
            s0[r] = s0[r] * E2(m0[r] - nm) + os * E2(om - nm);
            m0[r] = nm;
            om = __shfl_xor(m1[r], off); os = __shfl_xor(s1[r], off);
            nm = fmaxf(m1[r], om);
            s1[r] = s1[r] * E2(m1[r] - nm) + os * E2(om - nm);
            m1[r] = nm;
        }
    }
    if (l15 == 0) {
        #pragma unroll
        for (int r = 0; r < 4; ++r) {
            int row0 = R0 + (g << 2) + r;
            part[(row0 << 2) + q]        = make_float2(m0[r], s0[r]);
            part[((row0 + 16) << 2) + q] = make_float2(m1[r], s1[r]);
        }
    }

    // ---- centroid tail: wave 2 handles label bid (no atomics) ----
    float centv = 0.f;
    if (q == 2) {
        const int n = cnt[bid], bs = basep[bid];
        float ax = 0.f, ay = 0.f;
        const float2* z2 = (const float2*)z;
        for (int e0 = 0; e0 < n; e0 += 64) {
            int pe = (e0 + lane < n) ? perm[bs + e0 + lane] : 0;
            int c2 = n - e0; if (c2 > 64) c2 = 64;
            int j = 0;
            for (; j + 3 < c2; j += 4) {
                int r0 = __shfl(pe, j), r1 = __shfl(pe, j + 1);
                int r2 = __shfl(pe, j + 2), r3 = __shfl(pe, j + 3);
                float2 v0 = z2[((size_t)r0 << 6) + lane];
                float2 v1 = z2[((size_t)r1 << 6) + lane];
                float2 v2 = z2[((size_t)r2 << 6) + lane];
                float2 v3 = z2[((size_t)r3 << 6) + lane];
                ax += v0.x + v1.x + v2.x + v3.x;
                ay += v0.y + v1.y + v2.y + v3.y;
            }
            for (; j < c2; ++j) {
                int r0 = __shfl(pe, j);
                float2 v0 = z2[((size_t)r0 << 6) + lane];
                ax += v0.x; ay += v0.y;
            }
        }
        float ssq = ax * ax + ay * ay;
        #pragma unroll
        for (int off = 32; off; off >>= 1) ssq += __shfl_xor(ssq, off);
        centv = ssq / fmaxf((float)n, 1.f);
    }

    // ---- per-wave slot store (replaces ALL same-line atomics) ----
    if (lane == 0) {
        float4 o;
        o.x = hp;
        o.y = (q == 0) ? sp : 0.f;
        o.z = (q == 1) ? sp : 0.f;
        o.w = centv;
        wsum[gw] = o;
    }
}

// ---- merge the four M-quarter partials per row -> per-block lse partial ----
__global__ void mergeL(const float4* __restrict__ part4, float* __restrict__ lsePart) {
    __shared__ float wpart[4];
    int t = blockIdx.x * 256 + threadIdx.x;   // 0..65535 rows
    float4 A = part4[t << 1], Bq = part4[(t << 1) + 1];
    float nm = fmaxf(fmaxf(A.x, A.z), fmaxf(Bq.x, Bq.z));
    float s = A.y * E2(A.x - nm) + A.w * E2(A.z - nm)
            + Bq.y * E2(Bq.x - nm) + Bq.w * E2(Bq.z - nm);
    float lse = nm + LG2(s);
    #pragma unroll
    for (int off = 32; off; off >>= 1) lse += __shfl_xor(lse, off);
    if ((threadIdx.x & 63) == 0) wpart[threadIdx.x >> 6] = lse;
    __syncthreads();
    if (threadIdx.x == 0)
        lsePart[blockIdx.x] = wpart[0] + wpart[1] + wpart[2] + wpart[3];
}

// ---- final: sum 8192 wave slots + 256 lse partials, write output ----
__global__ void finalR(const float4* __restrict__ wsum,
                       const float* __restrict__ lsePart,
                       float* __restrict__ out) {
    __shared__ float red[5][4];
    int t = threadIdx.x, lane = t & 63, w = t >> 6;
    float hp = 0.f, pos = 0.f, zsq = 0.f, cent = 0.f, lse = 0.f;
    #pragma unroll
    for (int i = 0; i < 32; ++i) {
        float4 v = wsum[i * 256 + t];
        hp += v.x; pos += v.y; zsq += v.z; cent += v.w;
    }
    lse = lsePart[t];
    #pragma unroll
    for (int off = 32; off; off >>= 1) {
        hp  += __shfl_xor(hp, off);
        pos += __shfl_xor(pos, off);
        zsq += __shfl_xor(zsq, off);
        cent += __shfl_xor(cent, off);
        lse += __shfl_xor(lse, off);
    }
    if (lane == 0) {
        red[0][w] = hp; red[1][w] = pos; red[2][w] = zsq; red[3][w] = cent; red[4][w] = lse;
    }
    __syncthreads();
    if (t == 0) {
        float H = red[0][0] + red[0][1] + red[0][2] + red[0][3];
        float P = red[1][0] + red[1][1] + red[1][2] + red[1][3];
        float Z = red[2][0] + red[2][1] + red[2][2] + red[2][3];
        float C = red[3][0] + red[3][1] + red[3][2] + red[3][3];
        float L = red[4][0] + red[4][1] + red[4][2] + red[4][3];
        float lc   = (LN2 * L - 5.0f * P) * (1.0f / 65536.0f);
        float cent2 = (Z - C) * (1.0f / 8388608.0f);
        float hal  = H * (1.0f / 16777216.0f);
        out[0] = lc + 0.05f * cent2 + 0.1f * hal;
    }
}

extern "C" void kernel_launch(void* const* d_in, const int* in_sizes, int n_in,
                              void* d_out, int out_size, void* d_ws, size_t ws_size,
                              hipStream_t stream) {
    const float* z      = (const float*)d_in[0];
    const float* he     = (const float*)d_in[1];
    const float* hc     = (const float*)d_in[2];
    const float* anc    = (const float*)d_in[3];
    const int*   labels = (const int*)d_in[4];

    char* ws = (char*)d_ws;
    int*    cnt     = (int*)(ws + WS_CNT);
    int*    basep   = (int*)(ws + WS_BASE);
    int*    cursor  = (int*)(ws + WS_CUR);
    int*    perm    = (int*)(ws + WS_PERM);
    __bf16* ancb    = (__bf16*)(ws + WS_ANC);
    float2* part    = (float2*)(ws + WS_PART);
    float4* wsum    = (float4*)(ws + WS_WSUM);
    float*  lsePart = (float*)(ws + WS_LSE);

    hipMemsetAsync(d_ws, 0, WS_ZERO, stream);
    prepHist<<<256, 256, 0, stream>>>(anc, ancb, labels, cnt);
    scanK<<<1, 256, 0, stream>>>(cnt, basep, cursor);
    scatK<<<256, 256, 0, stream>>>(labels, cursor, perm);
    uniK<<<2048, 256, 0, stream>>>(z, he, hc, anc, labels, ancb, cnt, basep, perm, wsum, part);
    mergeL<<<256, 256, 0, stream>>>((const float4*)part, lsePart);
    finalR<<<1, 256, 0, stream>>>(wsum, lsePart, (float*)d_out);
}